// Round 7
// baseline (359.735 us; speedup 1.0000x reference)
//
#include <hip/hip_runtime.h>
#include <hip/hip_bf16.h>

// KNN_itc: out[b][n] = sum over support descriptors m (441) of top-3 (over 441
// query descriptors) cosine similarities, C=640, bf16 MFMA.
//
// R7:
//  - prep_kernel : block=(img, 64-row hw tile, 128-ch slab), 2800 blocks.
//    Single read pass; packs UNNORMALIZED bf16 fragment-linear chunks
//    (chunk[(img*28+rb)*20+kt], lane l's fragment at byte l*16); writes
//    per-slab sumsq partials to normPart (non-atomic, no memset needed).
//  - gemm_top3   : 448 thr (7 waves). Wave OWNS its 4 row-blocks -> A comes
//    straight from global as coalesced 1KiB fragment loads (L2-hot, XCD
//    swizzle), 1-kt-deep prefetch. Only B goes through LDS: two 40KB halves,
//    so the K-loop has ZERO barriers (160 MFMA/wave per barrier-pair).
//    rsqrt(normPart sums) computed in-kernel; in-register top-3 + shuffle
//    merge + one atomicAdd per block.

#define B_IMGS 75
#define N_CLS  5
#define C_DIM  640
#define HW     441
#define HWP    448
#define NKT    20            // 640 / 32 k-chunks
#define NRB    28            // 448 / 16 row-blocks per image
#define CHUNK  512           // 16 rows x 32 k elems = 1 KiB

typedef __attribute__((ext_vector_type(8))) short  short8;   // 8 x bf16
typedef __attribute__((ext_vector_type(4))) float  float4v;  // MFMA acc

__device__ __forceinline__ void ins3(float& t0, float& t1, float& t2, float v) {
    float m  = fminf(t0, v);
    t0 = fmaxf(t0, v);
    float m2 = fminf(t1, m);
    t1 = fmaxf(t1, m);
    t2 = fmaxf(t2, m2);
}

__device__ __forceinline__ short bf16bits(float x) {
    __hip_bfloat16 h = __float2bfloat16(x);
    return *(short*)&h;
}

__device__ __forceinline__ void glds16(const __hip_bfloat16* g, __hip_bfloat16* l) {
    __builtin_amdgcn_global_load_lds(
        (const __attribute__((address_space(1))) unsigned int*)g,
        (__attribute__((address_space(3))) unsigned int*)l, 16, 0, 0);
}

// ---- prepass: single-read pack + sumsq partials (non-atomic) ----
// block = (img 0..79, h0 0..6, cs 0..4); 2800 blocks x 256 threads
__global__ __launch_bounds__(256)
void prep_kernel(const float* __restrict__ q, const float* __restrict__ S,
                 __hip_bfloat16* __restrict__ qn2, __hip_bfloat16* __restrict__ sn2,
                 float* __restrict__ normPart) {
    __shared__ float tile[128][65];     // 33.3 KB
    __shared__ float part[4][64];

    int bid = blockIdx.x;
    int img = bid / 35;                 // 0..79 (0..74 = q, 75..79 = S)
    int rem = bid % 35;
    int h0  = rem / 5;                  // 64-row hw tile
    int cs  = rem % 5;                  // 128-channel slab
    const float* src; __hip_bfloat16* dst;
    if (img < B_IMGS) {
        src = q + (size_t)img * C_DIM * HW;
        dst = qn2 + (size_t)img * NRB * NKT * CHUNK;
    } else {
        src = S + (size_t)(img - B_IMGS) * C_DIM * HW;
        dst = sn2 + (size_t)(img - B_IMGS) * NRB * NKT * CHUNK;
    }
    int t  = threadIdx.x;
    int hl = t & 63;
    int p  = t >> 6;                    // 32-channel slice within the slab
    int hw = h0 * 64 + hl;
    bool ok = hw < HW;

    float ss = 0.f;
#pragma unroll
    for (int i = 0; i < 32; ++i) {
        int cl = p * 32 + i;
        float v = ok ? src[(size_t)(cs * 128 + cl) * HW + hw] : 0.f;  // coalesced
        tile[cl][hl] = v;
        ss += v * v;
    }
    part[p][hl] = ss;
    __syncthreads();
    if (t < 64) {   // pad rows get 0 naturally (v=0 above)
        float tot = part[0][t] + part[1][t] + part[2][t] + part[3][t];
        normPart[((size_t)cs * 80 + img) * HWP + h0 * 64 + t] = tot;
    }

    // pack: fragment-linear chunks, 1KiB coalesced stores
    int rbl   = t >> 6;                 // row-block within the 64-row tile
    int l     = t & 63;
    int seg   = l >> 4;                 // k-segment (8 elems)
    int row16 = l & 15;
#pragma unroll
    for (int ktl = 0; ktl < 4; ++ktl) { // 4 k-chunks in this 128-ch slab
        short8 v;
#pragma unroll
        for (int j = 0; j < 8; ++j)
            v[j] = bf16bits(tile[ktl * 32 + seg * 8 + j][rbl * 16 + row16]);
        size_t coff = ((size_t)(h0 * 4 + rbl) * NKT + cs * 4 + ktl) * CHUNK;
        *(short8*)(dst + coff + l * 8) = v;
    }
}

// ------------- gemm + fused top-3: barrier-free K-loop -------------
__global__ __launch_bounds__(448, 3)
void gemm_top3_kernel(const __hip_bfloat16* __restrict__ qn2,
                      const __hip_bfloat16* __restrict__ sn2,
                      const float* __restrict__ normPart,
                      float* __restrict__ out) {
    __shared__ __hip_bfloat16 Bs[40 * CHUNK];   // 40 KiB: half of B (4 jb x 10 kt)
    __shared__ float mrg[7][64][3];
    __shared__ float sInvQ[HWP];
    __shared__ float sInvS[64];

    // XCD-grouping swizzle: all 35 (n,mt) blocks of image b on one XCD
    int id  = blockIdx.x;
    int xcd = id & 7;
    int j8  = id >> 3;
    int b   = (j8 / 35) * 8 + xcd;
    if (b >= B_IMGS) return;
    int inner = j8 % 35;
    int n  = inner / 7;
    int mt = inner % 7;

    int tid  = threadIdx.x;
    int w    = tid >> 6;                // 0..6
    int l    = tid & 63;
    int c16  = l & 15;
    int quad = l >> 4;

    const __hip_bfloat16* qA = qn2 + (size_t)b * NRB * NKT * CHUNK;
    const __hip_bfloat16* qB = sn2 + ((size_t)n * NRB + mt * 4) * NKT * CHUNK;

    // --- stage half 0 of B (async, in flight during sInv computation) ---
#pragma unroll
    for (int i = 0; i < 6; ++i) {
        int c = w + i * 7;
        if (c < 40) {
            const __hip_bfloat16* g =
                qB + ((size_t)(c / 10) * NKT + (c % 10)) * CHUNK;
            glds16(g + l * 8, Bs + c * CHUNK + l * 8);
        }
    }

    // --- inv norms for this block's rows/cols (overlaps glds) ---
    {
        float s = 0.f;
#pragma unroll
        for (int cs = 0; cs < 5; ++cs)
            s += normPart[((size_t)cs * 80 + b) * HWP + tid];
        sInvQ[tid] = (tid < HW) ? rsqrtf(s) : 0.f;
        if (tid < 64) {
            float s2 = 0.f;
#pragma unroll
            for (int cs = 0; cs < 5; ++cs)
                s2 += normPart[((size_t)cs * 80 + B_IMGS + n) * HWP + mt * 64 + tid];
            sInvS[tid] = ((mt * 64 + tid) < HW) ? rsqrtf(s2) : 0.f;
        }
    }

    // --- A fragment base pointers (wave-exclusive rows; coalesced 1KiB loads) ---
    const __hip_bfloat16* aB[4];
#pragma unroll
    for (int r = 0; r < 4; ++r)
        aB[r] = qA + (size_t)(w * 4 + r) * NKT * CHUNK + l * 8;

    short8 a_c[4];
#pragma unroll
    for (int r = 0; r < 4; ++r) a_c[r] = *(const short8*)(aB[r]);   // ktg = 0

    float4v acc[4][4];
#pragma unroll
    for (int r = 0; r < 4; ++r)
#pragma unroll
        for (int j = 0; j < 4; ++j)
            acc[r][j] = (float4v){0.f, 0.f, 0.f, 0.f};

    __syncthreads();                      // half-0 staging + sInv visible

#pragma unroll
    for (int ktg = 0; ktg < NKT; ++ktg) {
        if (ktg == 10) {                  // restage: half 1 of B
            __syncthreads();              // half-0 reads complete
#pragma unroll
            for (int i = 0; i < 6; ++i) {
                int c = w + i * 7;
                if (c < 40) {
                    const __hip_bfloat16* g =
                        qB + ((size_t)(c / 10) * NKT + 10 + (c % 10)) * CHUNK;
                    glds16(g + l * 8, Bs + c * CHUNK + l * 8);
                }
            }
            __syncthreads();              // half-1 staged
        }
        short8 a_n[4];
        if (ktg + 1 < NKT) {
#pragma unroll
            for (int r = 0; r < 4; ++r)
                a_n[r] = *(const short8*)(aB[r] + (ktg + 1) * CHUNK);
        }
        const int kk = ktg % 10;          // static after unroll
        short8 bf[4];
#pragma unroll
        for (int j = 0; j < 4; ++j)
            bf[j] = *(const short8*)(Bs + (j * 10 + kk) * CHUNK + l * 8);  // linear
#pragma unroll
        for (int r = 0; r < 4; ++r)
#pragma unroll
            for (int j = 0; j < 4; ++j)
                acc[r][j] = __builtin_amdgcn_mfma_f32_16x16x32_bf16(
                    a_c[r], bf[j], acc[r][j], 0, 0, 0);
        if (ktg + 1 < NKT) {
#pragma unroll
            for (int r = 0; r < 4; ++r) a_c[r] = a_n[r];
        }
    }

    // ---- top-3 over this wave's 64 rows (v = acc * invq[row]) ----
    float T0[4], T1[4], T2[4];
#pragma unroll
    for (int j = 0; j < 4; ++j) { T0[j] = -1e30f; T1[j] = -1e30f; T2[j] = -1e30f; }
#pragma unroll
    for (int r = 0; r < 4; ++r)
#pragma unroll
        for (int g = 0; g < 4; ++g) {
            int row = w * 64 + r * 16 + quad * 4 + g;   // C layout: row=quad*4+reg
            float iv = sInvQ[row];                       // broadcast-heavy LDS read
            bool valid = row < HW;
#pragma unroll
            for (int j = 0; j < 4; ++j) {
                float v = valid ? acc[r][j][g] * iv : -1e30f;
                ins3(T0[j], T1[j], T2[j], v);
            }
        }

    // quad-butterfly merge (rows spread over lane bits 4,5)
#pragma unroll
    for (int j = 0; j < 4; ++j) {
#pragma unroll
        for (int d = 16; d <= 32; d <<= 1) {
            float o0 = __shfl_xor(T0[j], d, 64);
            float o1 = __shfl_xor(T1[j], d, 64);
            float o2 = __shfl_xor(T2[j], d, 64);
            ins3(T0[j], T1[j], T2[j], o0);
            ins3(T0[j], T1[j], T2[j], o1);
            ins3(T0[j], T1[j], T2[j], o2);
        }
    }

    // cross-wave merge via LDS
    if (quad == 0) {
#pragma unroll
        for (int j = 0; j < 4; ++j) {
            mrg[w][j * 16 + c16][0] = T0[j];
            mrg[w][j * 16 + c16][1] = T1[j];
            mrg[w][j * 16 + c16][2] = T2[j];
        }
    }
    __syncthreads();
    if (tid < 64) {
        int col = tid;
        float t0 = mrg[0][col][0], t1 = mrg[0][col][1], t2 = mrg[0][col][2];
#pragma unroll
        for (int ww = 1; ww < 7; ++ww) {
            ins3(t0, t1, t2, mrg[ww][col][0]);
            ins3(t0, t1, t2, mrg[ww][col][1]);
            ins3(t0, t1, t2, mrg[ww][col][2]);
        }
        float isv = sInvS[col];
        float s = (mt * 64 + col < HW) ? (t0 + t1 + t2) * isv : 0.f;
#pragma unroll
        for (int d = 32; d >= 1; d >>= 1) s += __shfl_xor(s, d, 64);
        if (tid == 0) atomicAdd(&out[b * N_CLS + n], s);
    }
}

extern "C" void kernel_launch(void* const* d_in, const int* in_sizes, int n_in,
                              void* d_out, int out_size, void* d_ws, size_t ws_size,
                              hipStream_t stream) {
    const float* q = (const float*)d_in[0];
    const float* S = (const float*)d_in[1];
    float* out = (float*)d_out;

    char* ws = (char*)d_ws;
    size_t off = 0;
    __hip_bfloat16* qn2 = (__hip_bfloat16*)(ws + off);
    off += (size_t)B_IMGS * NRB * NKT * CHUNK * 2;  off = (off + 255) & ~(size_t)255;
    __hip_bfloat16* sn2 = (__hip_bfloat16*)(ws + off);
    off += (size_t)N_CLS * NRB * NKT * CHUNK * 2;   off = (off + 255) & ~(size_t)255;
    float* normPart = (float*)(ws + off);           // [5][80][HWP], written fully

    hipMemsetAsync(d_out, 0, (size_t)out_size * sizeof(float), stream);

    prep_kernel<<<dim3(80 * 35), dim3(256), 0, stream>>>(q, S, qn2, sn2, normPart);
    // 8 XCD groups x 350 slots; dead blocks (b>=75) exit immediately
    gemm_top3_kernel<<<dim3(8 * 350), dim3(448), 0, stream>>>(qn2, sn2, normPart, out);
}

// Round 8
// 346.979 us; speedup vs baseline: 1.0368x; 1.0368x over previous
//
#include <hip/hip_runtime.h>
#include <hip/hip_bf16.h>

// KNN_itc: out[b][n] = sum over support descriptors m (441) of top-3 (over 441
// query descriptors) cosine similarities, C=640, bf16 MFMA.
//
// R8:
//  - prep_kernel : block=(img, 64-ch slab), 800 blocks. Reads a CONTIGUOUS
//    113KB f32 region (the R1..R7 preps all read 256B strided segments ->
//    ~650 GB/s -> the constant ~140us gap). Stores bf16 [k][row] LDS tile,
//    accumulates sumsq partials (deferred normalization), packs
//    fragment-linear chunks: chunk[(img*28+rb)*20+kt], lane l's MFMA
//    fragment (row=l&15, k=(l>>4)*8+j) at elem offset l*8.
//  - gemm_top3   : R5's proven m97 structure (best: 142us): BK=64 slab = 64
//    chunks (56 A + 8 B) via global_load_lds w=16, 2 barriers/slab, 10 slabs,
//    56 MFMA/wave/slab. Changes vs R5: fragment-linear ds_read (conflicts
//    9.2e6 -> 0) and in-kernel rsqrt of normPart sums (norm applied in
//    epilogue; kills the finish kernel). One atomicAdd per block.

#define B_IMGS 75
#define N_CLS  5
#define N_IMGS 80            // 75 query + 5 support
#define C_DIM  640
#define HW     441
#define HWP    448
#define NKT    20            // 640 / 32 k-chunks
#define NRB    28            // 448 / 16 row-blocks per image
#define CHUNK  512           // 16 rows x 32 k elems = 1 KiB

typedef __attribute__((ext_vector_type(8))) short  short8;   // 8 x bf16
typedef __attribute__((ext_vector_type(4))) float  float4v;  // MFMA acc

__device__ __forceinline__ void ins3(float& t0, float& t1, float& t2, float v) {
    float m  = fminf(t0, v);
    t0 = fmaxf(t0, v);
    float m2 = fminf(t1, m);
    t1 = fmaxf(t1, m);
    t2 = fmaxf(t2, m2);
}

__device__ __forceinline__ void glds16(const __hip_bfloat16* g, __hip_bfloat16* l) {
    __builtin_amdgcn_global_load_lds(
        (const __attribute__((address_space(1))) unsigned int*)g,
        (__attribute__((address_space(3))) unsigned int*)l, 16, 0, 0);
}

// ---- prepass: contiguous read + transpose + bf16 pack + sumsq partials ----
// block = (img 0..79, cs 0..9: 64-channel slab); 800 blocks x 256 threads
__global__ __launch_bounds__(256)
void prep_kernel(const float* __restrict__ q, const float* __restrict__ S,
                 __hip_bfloat16* __restrict__ pk, float* __restrict__ normPart) {
    __shared__ __hip_bfloat16 tile[64][449];   // [k_local][hw]; 57.4 KB
                                               // 449: quad-stride 8*898B/4 == 4 mod 32
    int bid = blockIdx.x;
    int img = bid / 10;                 // 0..79 (0..74 = q, 75..79 = S)
    int cs  = bid % 10;                 // 64-channel slab
    const float* src = (img < B_IMGS)
        ? q + (size_t)img * C_DIM * HW
        : S + (size_t)(img - B_IMGS) * C_DIM * HW;
    __hip_bfloat16* dst = pk + (size_t)img * NRB * NKT * CHUNK;
    const float* base = src + (size_t)cs * 64 * HW;   // contiguous 64x441 f32

    int t = threadIdx.x;
    bool t2ok = (t < HW - 256);         // 185: second segment valid
    float ss0 = 0.f, ss1 = 0.f;
#pragma unroll 4
    for (int cl = 0; cl < 64; ++cl) {
        float v0 = base[cl * HW + t];                       // coalesced, dense
        float v1 = t2ok ? base[cl * HW + 256 + t] : 0.f;
        ss0 += v0 * v0;
        ss1 += v1 * v1;
        tile[cl][t] = __float2bfloat16(v0);
        if (t < HWP - 256) tile[cl][256 + t] = __float2bfloat16(v1);  // pads -> 0
    }
    normPart[((size_t)cs * N_IMGS + img) * HWP + t] = ss0;
    if (t < HWP - 256)
        normPart[((size_t)cs * N_IMGS + img) * HWP + 256 + t] = ss1;
    __syncthreads();

    // pack: fragment-linear chunks; per (rb,kk) a 1KiB coalesced wave store
    int l     = t & 63;
    int wg    = t >> 6;
    int row16 = l & 15;
    int quad  = l >> 4;
#pragma unroll
    for (int i = 0; i < 7; ++i) {
        int rb = i * 4 + wg;
#pragma unroll
        for (int kk = 0; kk < 2; ++kk) {
            short8 v;
#pragma unroll
            for (int j = 0; j < 8; ++j) {
                __hip_bfloat16 h = tile[kk * 32 + quad * 8 + j][rb * 16 + row16];
                v[j] = *(short*)&h;
            }
            *(short8*)(dst + ((size_t)rb * NKT + cs * 2 + kk) * CHUNK + l * 8) = v;
        }
    }
}

// ------------- gemm + fused top-3: R5 structure, fragment-linear LDS -------------
__global__ __launch_bounds__(256, 2)
void gemm_top3_kernel(const __hip_bfloat16* __restrict__ pk,
                      const float* __restrict__ normPart,
                      float* __restrict__ out) {
    __shared__ __hip_bfloat16 sbuf[64 * CHUNK];   // 64 KiB: 56 A + 8 B chunks
    __shared__ float mrg[4][64][3];
    __shared__ float sInvQ[HWP];
    __shared__ float sInvS[64];

    // XCD-grouping swizzle: all 35 (n,mt) blocks of image b on one XCD
    int id  = blockIdx.x;
    int xcd = id & 7;
    int j8  = id >> 3;
    int b   = (j8 / 35) * 8 + xcd;
    if (b >= B_IMGS) return;
    int inner = j8 % 35;
    int n  = inner / 7;
    int mt = inner % 7;

    int tid  = threadIdx.x;
    int w    = tid >> 6;
    int l    = tid & 63;
    int c16  = l & 15;
    int quad = l >> 4;

    const __hip_bfloat16* qA = pk + (size_t)b * NRB * NKT * CHUNK;
    const __hip_bfloat16* qB = pk + ((size_t)(B_IMGS + n) * NRB + mt * 4) * NKT * CHUNK;

    // --- stage slab 0 (async; overlaps the norm computation below) ---
#pragma unroll
    for (int i = 0; i < 16; ++i) {
        int cid = w * 16 + i;
        const __hip_bfloat16* g = (cid < 56)
            ? qA + ((size_t)(cid >> 1) * NKT + (cid & 1)) * CHUNK
            : qB + ((size_t)((cid - 56) >> 1) * NKT + (cid & 1)) * CHUNK;
        glds16(g + l * 8, sbuf + cid * CHUNK + l * 8);
    }

    // --- inv norms from the 10 per-slab partials (L2-hot, overlaps glds) ---
    {
        float s0 = 0.f, s1 = 0.f, s2 = 0.f;
#pragma unroll
        for (int cs = 0; cs < 10; ++cs) {
            const float* npq = normPart + ((size_t)cs * N_IMGS + b) * HWP;
            s0 += npq[tid];
            if (tid < HWP - 256) s1 += npq[256 + tid];
            if (tid < 64)
                s2 += normPart[((size_t)cs * N_IMGS + B_IMGS + n) * HWP + mt * 64 + tid];
        }
        sInvQ[tid] = (tid < HW) ? rsqrtf(s0) : 0.f;
        if (tid < HWP - 256)
            sInvQ[256 + tid] = ((256 + tid) < HW) ? rsqrtf(s1) : 0.f;
        if (tid < 64)
            sInvS[tid] = ((mt * 64 + tid) < HW) ? rsqrtf(s2) : 0.f;
    }

    float4v acc[7][4];
#pragma unroll
    for (int r = 0; r < 7; ++r)
#pragma unroll
        for (int j = 0; j < 4; ++j)
            acc[r][j] = (float4v){0.f, 0.f, 0.f, 0.f};

    __syncthreads();                     // slab-0 staging + norms visible

    for (int s = 0; s < 10; ++s) {
        // compute on slab s
#pragma unroll
        for (int kk = 0; kk < 2; ++kk) {
            short8 a[7], bf[4];
#pragma unroll
            for (int r = 0; r < 7; ++r)
                a[r] = *(const short8*)(sbuf + ((r * 4 + w) * 2 + kk) * CHUNK + l * 8);
#pragma unroll
            for (int j = 0; j < 4; ++j)
                bf[j] = *(const short8*)(sbuf + (56 + j * 2 + kk) * CHUNK + l * 8);
#pragma unroll
            for (int r = 0; r < 7; ++r)
#pragma unroll
                for (int j = 0; j < 4; ++j)
                    acc[r][j] = __builtin_amdgcn_mfma_f32_16x16x32_bf16(
                        a[r], bf[j], acc[r][j], 0, 0, 0);
        }
        if (s + 1 < 10) {
            __syncthreads();             // slab-s reads complete
#pragma unroll
            for (int i = 0; i < 16; ++i) {
                int cid = w * 16 + i;
                const __hip_bfloat16* g = (cid < 56)
                    ? qA + ((size_t)(cid >> 1) * NKT + 2 * (s + 1) + (cid & 1)) * CHUNK
                    : qB + ((size_t)((cid - 56) >> 1) * NKT + 2 * (s + 1) + (cid & 1)) * CHUNK;
                glds16(g + l * 8, sbuf + cid * CHUNK + l * 8);
            }
            __syncthreads();             // slab s+1 staged
        }
    }

    // ---- in-register top-3 over this wave's 112 rows (v = acc * invq[row]) ----
    float T0[4], T1[4], T2[4];
#pragma unroll
    for (int j = 0; j < 4; ++j) { T0[j] = -1e30f; T1[j] = -1e30f; T2[j] = -1e30f; }
#pragma unroll
    for (int r = 0; r < 7; ++r)
#pragma unroll
        for (int g = 0; g < 4; ++g) {
            int row = r * 64 + w * 16 + quad * 4 + g;   // C layout: row=quad*4+reg
            float iv = sInvQ[row];
            bool valid = row < HW;
#pragma unroll
            for (int j = 0; j < 4; ++j) {
                float v = valid ? acc[r][j][g] * iv : -1e30f;
                ins3(T0[j], T1[j], T2[j], v);
            }
        }

    // quad-butterfly merge (rows spread over lane bits 4,5)
#pragma unroll
    for (int j = 0; j < 4; ++j) {
#pragma unroll
        for (int d = 16; d <= 32; d <<= 1) {
            float o0 = __shfl_xor(T0[j], d, 64);
            float o1 = __shfl_xor(T1[j], d, 64);
            float o2 = __shfl_xor(T2[j], d, 64);
            ins3(T0[j], T1[j], T2[j], o0);
            ins3(T0[j], T1[j], T2[j], o1);
            ins3(T0[j], T1[j], T2[j], o2);
        }
    }

    // cross-wave merge via LDS
    if (quad == 0) {
#pragma unroll
        for (int j = 0; j < 4; ++j) {
            mrg[w][j * 16 + c16][0] = T0[j];
            mrg[w][j * 16 + c16][1] = T1[j];
            mrg[w][j * 16 + c16][2] = T2[j];
        }
    }
    __syncthreads();
    if (tid < 64) {
        int col = tid;
        float t0 = mrg[0][col][0], t1 = mrg[0][col][1], t2 = mrg[0][col][2];
#pragma unroll
        for (int ww = 1; ww < 4; ++ww) {
            ins3(t0, t1, t2, mrg[ww][col][0]);
            ins3(t0, t1, t2, mrg[ww][col][1]);
            ins3(t0, t1, t2, mrg[ww][col][2]);
        }
        float isv = sInvS[col];
        float s = (mt * 64 + col < HW) ? (t0 + t1 + t2) * isv : 0.f;
#pragma unroll
        for (int d = 32; d >= 1; d >>= 1) s += __shfl_xor(s, d, 64);
        if (tid == 0) atomicAdd(&out[b * N_CLS + n], s);
    }
}

extern "C" void kernel_launch(void* const* d_in, const int* in_sizes, int n_in,
                              void* d_out, int out_size, void* d_ws, size_t ws_size,
                              hipStream_t stream) {
    const float* q = (const float*)d_in[0];
    const float* S = (const float*)d_in[1];
    float* out = (float*)d_out;

    char* ws = (char*)d_ws;
    size_t off = 0;
    __hip_bfloat16* pk = (__hip_bfloat16*)(ws + off);     // 80 imgs packed
    off += (size_t)N_IMGS * NRB * NKT * CHUNK * 2;  off = (off + 255) & ~(size_t)255;
    float* normPart = (float*)(ws + off);                 // [10][80][HWP]

    hipMemsetAsync(d_out, 0, (size_t)out_size * sizeof(float), stream);

    prep_kernel<<<dim3(N_IMGS * 10), dim3(256), 0, stream>>>(q, S, pk, normPart);
    // 8 XCD groups x 350 slots; dead blocks (b>=75) exit immediately
    gemm_top3_kernel<<<dim3(8 * 350), dim3(256), 0, stream>>>(pk, normPart, out);
}